// Round 4
// baseline (339.626 us; speedup 1.0000x reference)
//
#include <hip/hip_runtime.h>
#include <cstdint>

#define NTOK 8192

typedef __attribute__((ext_vector_type(4))) float f32x4;
typedef __attribute__((ext_vector_type(8))) short s16x8;

__device__ __forceinline__ short f2bf(float f) {
  union { float f; unsigned u; } x; x.f = f;
  unsigned r = x.u + 0x7FFFu + ((x.u >> 16) & 1u);
  return (short)(r >> 16);
}
__device__ __forceinline__ float bf2f(short s) {
  union { float f; unsigned u; } x;
  x.u = ((unsigned)(unsigned short)s) << 16;
  return x.f;
}
__device__ __forceinline__ void gl_lds16(const void* g, void* l) {
  __builtin_amdgcn_global_load_lds((const unsigned int*)g, (unsigned int*)l, 16, 0, 0);
}

// ---------------------------------------------------------------------------
// K1: transpose (B,DIM,L)->(B,L,DIM) + LayerNorm both inputs (bf16 out),
// seqT f32; also converts the 5 weight matrices to bf16.
// grid: 256 blocks, 256 threads
// ---------------------------------------------------------------------------
__global__ __launch_bounds__(256) void ln_transpose_kernel(
    const float* __restrict__ in0, const float* __restrict__ in1,
    const float* __restrict__ w0, const float* __restrict__ b0,
    const float* __restrict__ w1, const float* __restrict__ b1,
    const float* __restrict__ wxp, const float* __restrict__ wzp,
    const float* __restrict__ wop, const float* __restrict__ wcp,
    const float* __restrict__ xwf, const float* __restrict__ xwb,
    short* __restrict__ Wx, short* __restrict__ Wz,
    short* __restrict__ Wo, short* __restrict__ Wc, short* __restrict__ Wxp,
    short* __restrict__ xlnz, float* __restrict__ seqT)
{
  __shared__ float tile[32 * 257];
  __shared__ float mu[32], rs[32];
  const int tid = threadIdx.x;
  const int b  = blockIdx.x >> 7;
  const int l0 = (blockIdx.x & 127) << 5;

  // weight conversion (grid-stride over 540672 elements)
  for (int idx = (int)blockIdx.x * 256 + tid; idx < 540672; idx += 65536) {
    if (idx < 65536)       Wx[idx] = f2bf(wxp[idx]);
    else if (idx < 131072) Wz[idx - 65536] = f2bf(wzp[idx - 65536]);
    else if (idx < 196608) Wo[idx - 131072] = f2bf(wop[idx - 131072]);
    else if (idx < 524288) {
      int k = idx - 196608;            // 1280x256 padded
      Wc[k] = ((k >> 8) < 1200) ? f2bf(wcp[k]) : (short)0;
    } else {
      int k = idx - 524288;            // 2 x 32 x 256 xproj weights
      int j = k & 8191;
      Wxp[k] = f2bf((k >> 13) ? xwb[j] : xwf[j]);
    }
  }

  for (int pass = 0; pass < 2; ++pass) {
    const float* in = pass ? in1 : in0;
    #pragma unroll 8
    for (int i = 0; i < 32; ++i) {
      int e = (i << 8) + tid;
      int c = e >> 5, lo = e & 31;
      tile[lo * 257 + c] = in[((size_t)(b * 256 + c) << 12) + l0 + lo];
    }
    __syncthreads();
    if (tid < 64) {
      int r = tid & 31, h = tid >> 5;
      float s = 0.f, ss = 0.f;
      #pragma unroll 16
      for (int c = h * 128; c < h * 128 + 128; ++c) {
        float v = tile[r * 257 + c];
        s += v; ss += v * v;
      }
      s  += __shfl_xor(s, 32, 64);
      ss += __shfl_xor(ss, 32, 64);
      if (h == 0) {
        float m = s * (1.f / 256.f);
        mu[r] = m;
        rs[r] = rsqrtf(ss * (1.f / 256.f) - m * m + 1e-5f);
      }
    }
    __syncthreads();
    const float* w  = pass ? w1 : w0;
    const float* bb = pass ? b1 : b0;
    float wv = w[tid], bv = bb[tid];
    #pragma unroll 8
    for (int i = 0; i < 32; ++i) {
      float v = tile[i * 257 + tid];
      int row = (pass ? 8192 : 0) + (b << 12) + l0 + i;
      xlnz[(size_t)row * 256 + tid] = f2bf((v - mu[i]) * rs[i] * wv + bv);
      if (pass == 0) seqT[(((size_t)b << 12) + l0 + i) * 256 + tid] = v;
    }
    __syncthreads();
  }
}

// ---------------------------------------------------------------------------
// K2: 128x128 bf16 MFMA GEMM (m97 structure), C[M,N] = A[M,256] * W[N,256]^T
// EPI 0: f32 store N=256; W switches W0->W1 at m>=Msplit (in_proj x|z)
// EPI 1: bf16 store + f32 ADD[(m&8191)*256+n]  (out_proj + skip, 3 heads)
// EPI 2: conv3d: transposed nontemporal f32x4 store + bias[n]
// ---------------------------------------------------------------------------
template <int EPI>
__global__ __launch_bounds__(256) void gemm_fast(
    const short* __restrict__ A, const short* __restrict__ W0,
    const short* __restrict__ W1, float* __restrict__ Cf,
    short* __restrict__ Cb, const float* __restrict__ ADD,
    const float* __restrict__ bias, int Msplit)
{
  __shared__ short As[4096];
  __shared__ short Bs[4096];
  const int tid  = threadIdx.x;
  const int lane = tid & 63, wave = tid >> 6;
  const int m0 = blockIdx.y << 7;
  const int n0 = blockIdx.x << 7;
  const short* W = (EPI == 0 && m0 >= Msplit) ? W1 : W0;

  const int sr = tid >> 2;
  const int sc = (tid & 3) << 3;
  const int mf = lane & 15, kq = lane >> 4;
  const int wm = (wave & 1) << 6, wn = (wave >> 1) << 6;

  const short* Ar0 = A + (size_t)(m0 + sr) * 256 + sc;
  const short* Ar1 = A + (size_t)(m0 + 64 + sr) * 256 + sc;
  const short* Br0 = W + (size_t)(n0 + sr) * 256 + sc;
  const short* Br1 = W + (size_t)(n0 + 64 + sr) * 256 + sc;
  short* AsW = &As[wave << 9];
  short* BsW = &Bs[wave << 9];

  f32x4 acc[4][4] = {};

  for (int kt = 0; kt < 256; kt += 32) {
    gl_lds16(Ar0 + kt, AsW);
    gl_lds16(Ar1 + kt, AsW + 2048);
    gl_lds16(Br0 + kt, BsW);
    gl_lds16(Br1 + kt, BsW + 2048);
    __syncthreads();
    s16x8 af[4], bfr[4];
    #pragma unroll
    for (int i = 0; i < 4; ++i)
      af[i] = *(const s16x8*)&As[((wm + (i << 4) + mf) << 5) + (kq << 3)];
    #pragma unroll
    for (int j = 0; j < 4; ++j)
      bfr[j] = *(const s16x8*)&Bs[((wn + (j << 4) + mf) << 5) + (kq << 3)];
    #pragma unroll
    for (int i = 0; i < 4; ++i)
      #pragma unroll
      for (int j = 0; j < 4; ++j)
        acc[i][j] = __builtin_amdgcn_mfma_f32_16x16x32_bf16(af[i], bfr[j], acc[i][j], 0, 0, 0);
    __syncthreads();
  }

  if (EPI == 0) {
    #pragma unroll
    for (int i = 0; i < 4; ++i) {
      int gm = m0 + wm + (i << 4) + (kq << 2);
      #pragma unroll
      for (int j = 0; j < 4; ++j) {
        int gn = n0 + wn + (j << 4) + mf;
        #pragma unroll
        for (int r = 0; r < 4; ++r)
          Cf[(size_t)(gm + r) * 256 + gn] = acc[i][j][r];
      }
    }
  } else if (EPI == 1) {
    #pragma unroll
    for (int i = 0; i < 4; ++i) {
      int gm = m0 + wm + (i << 4) + (kq << 2);
      #pragma unroll
      for (int j = 0; j < 4; ++j) {
        int gn = n0 + wn + (j << 4) + mf;
        #pragma unroll
        for (int r = 0; r < 4; ++r) {
          int tok = (gm + r) & 8191;
          float v = acc[i][j][r] + ADD[(size_t)tok * 256 + gn];
          Cb[(size_t)(gm + r) * 256 + gn] = f2bf(v);
        }
      }
    }
  } else {
    const int head = m0 >> 13, bb = (m0 >> 12) & 1, lb = m0 & 4095;
    float* obase = Cf + (size_t)head * (2u * 1200u * 4096u) + (size_t)bb * (1200u * 4096u);
    #pragma unroll
    for (int i = 0; i < 4; ++i) {
      int l = lb + wm + (i << 4) + (kq << 2);
      #pragma unroll
      for (int j = 0; j < 4; ++j) {
        int gn = n0 + wn + (j << 4) + mf;
        if (gn < 1200) {
          float bv = bias[gn];
          f32x4 v = acc[i][j];
          v[0] += bv; v[1] += bv; v[2] += bv; v[3] += bv;
          __builtin_nontemporal_store(v, (f32x4*)&obase[(size_t)gn * 4096 + l]);
        }
      }
    }
  }
}

// ---------------------------------------------------------------------------
// K3: conv1d+SiLU -> bf16 (xproj GEMM input only).
// grid 1024 = dir(2) x b(2) x ch(256), 256 threads (d)
// ---------------------------------------------------------------------------
__global__ __launch_bounds__(256) void conv_silu_b(
    const float* __restrict__ x,
    const float* __restrict__ cw0, const float* __restrict__ cb0,
    const float* __restrict__ cw1, const float* __restrict__ cb1,
    short* __restrict__ xcb)
{
  const int d = threadIdx.x;
  const int dir = blockIdx.x >> 9;
  const int b   = (blockIdx.x >> 8) & 1;
  const int t0  = (blockIdx.x & 255) << 4;
  const float* cw = dir ? cw1 : cw0;
  const float* cb = dir ? cb1 : cb0;
  const float w0 = cw[(d << 2)], w1 = cw[(d << 2) + 1],
              w2 = cw[(d << 2) + 2], w3 = cw[(d << 2) + 3];
  const float bias = cb[d];
  const size_t xb = ((size_t)b) << 12;
  short* orow = xcb + ((size_t)(dir << 13) + (b << 12) + t0) * 256 + d;
  float h0 = 0.f, h1 = 0.f, h2 = 0.f;
  #pragma unroll
  for (int i = 0; i < 3; ++i) {
    int ts = t0 - 3 + i; float v = 0.f;
    if (ts >= 0) { int tn = dir ? 4095 - ts : ts; v = x[(xb + tn) * 256 + d]; }
    h0 = h1; h1 = h2; h2 = v;
  }
  #pragma unroll
  for (int s = 0; s < 16; ++s) {
    int tn = dir ? 4095 - (t0 + s) : (t0 + s);
    float xv = x[(xb + tn) * 256 + d];
    float a = bias + w0 * h0 + w1 * h1 + w2 * h2 + w3 * xv;
    h0 = h1; h1 = h2; h2 = xv;
    orow[(size_t)s * 256] = f2bf(a / (1.f + __expf(-a)));
  }
}

// ---------------------------------------------------------------------------
// K4: xproj GEMM, no LDS, no barriers: dbl[16384,32] = xcb * Wxp[dir]^T
// grid 256 (64 rows each), 256 threads (4 independent waves of 16 rows)
// ---------------------------------------------------------------------------
__global__ __launch_bounds__(256) void gemm_n32(
    const short* __restrict__ A, const short* __restrict__ Wxp,
    float* __restrict__ Cdbl)
{
  const int lane = threadIdx.x & 63, wave = threadIdx.x >> 6;
  const int mf = lane & 15, kq = lane >> 4;
  const int m0 = ((int)blockIdx.x << 6) + (wave << 4);
  const short* W = Wxp + ((m0 >= 8192) ? 8192 : 0);
  const short* Arow = A + (size_t)(m0 + mf) * 256 + (kq << 3);
  const short* B0 = W + (size_t)mf * 256 + (kq << 3);
  const short* B1 = W + (size_t)(16 + mf) * 256 + (kq << 3);
  f32x4 acc[2] = {};
  #pragma unroll
  for (int kt = 0; kt < 256; kt += 32) {
    s16x8 af = *(const s16x8*)(Arow + kt);
    s16x8 b0 = *(const s16x8*)(B0 + kt);
    s16x8 b1 = *(const s16x8*)(B1 + kt);
    acc[0] = __builtin_amdgcn_mfma_f32_16x16x32_bf16(af, b0, acc[0], 0, 0, 0);
    acc[1] = __builtin_amdgcn_mfma_f32_16x16x32_bf16(af, b1, acc[1], 0, 0, 0);
  }
  #pragma unroll
  for (int j = 0; j < 2; ++j)
    #pragma unroll
    for (int r = 0; r < 4; ++r)
      Cdbl[(size_t)(m0 + (kq << 2) + r) * 32 + (j << 4) + mf] = acc[j][r];
}

// ---------------------------------------------------------------------------
// K5: scan phase-1: conv recompute -> dt -> per-chunk (P,Q).
// dbl read via wave-uniform (scalar) loads. grid 1024, 256 threads (d)
// ---------------------------------------------------------------------------
__global__ __launch_bounds__(256) void scan_p1(
    const float* __restrict__ x,
    const float* __restrict__ cw0, const float* __restrict__ cb0,
    const float* __restrict__ cw1, const float* __restrict__ cb1,
    const float* __restrict__ dbl,
    const float* __restrict__ dtw0, const float* __restrict__ dtb0,
    const float* __restrict__ dtw1, const float* __restrict__ dtb1,
    const float* __restrict__ Al0, const float* __restrict__ Al1,
    float* __restrict__ P, float* __restrict__ Q)
{
  const int d = threadIdx.x;
  const int dir = blockIdx.x >> 9;
  const int b   = (blockIdx.x >> 8) & 1;
  const int ch  = blockIdx.x & 255;
  const int t0  = ch << 4;
  const float* cw   = dir ? cw1 : cw0;
  const float* cb   = dir ? cb1 : cb0;
  const float* dtw  = dir ? dtw1 : dtw0;
  const float* dtb  = dir ? dtb1 : dtb0;
  const float* Alog = dir ? Al1 : Al0;
  const size_t xb = ((size_t)b) << 12;

  // conv1d + SiLU into registers
  float xc[16];
  {
    const float w0 = cw[(d << 2)], w1 = cw[(d << 2) + 1],
                w2 = cw[(d << 2) + 2], w3 = cw[(d << 2) + 3];
    const float bias = cb[d];
    float h0 = 0.f, h1 = 0.f, h2 = 0.f;
    #pragma unroll
    for (int i = 0; i < 3; ++i) {
      int ts = t0 - 3 + i; float v = 0.f;
      if (ts >= 0) { int tn = dir ? 4095 - ts : ts; v = x[(xb + tn) * 256 + d]; }
      h0 = h1; h1 = h2; h2 = v;
    }
    #pragma unroll
    for (int s = 0; s < 16; ++s) {
      int tn = dir ? 4095 - (t0 + s) : (t0 + s);
      float xv = x[(xb + tn) * 256 + d];
      float a = bias + w0 * h0 + w1 * h1 + w2 * h2 + w3 * xv;
      h0 = h1; h1 = h2; h2 = xv;
      xc[s] = a / (1.f + __expf(-a));
    }
  }

  float wrow[16];
  #pragma unroll
  for (int r = 0; r < 16; ++r) wrow[r] = dtw[(d << 4) + r];
  const float bias_dt = dtb[d];
  float Av[8], p[8], q[8];
  #pragma unroll
  for (int n = 0; n < 8; ++n) {
    Av[n] = -expf(Alog[(d << 3) + n]); p[n] = 1.f; q[n] = 0.f;
  }
  const float* drow = dbl + ((size_t)(dir << 13) + (b << 12) + t0) * 32;  // uniform
  #pragma unroll 4
  for (int s = 0; s < 16; ++s) {
    float a = bias_dt;
    #pragma unroll
    for (int r = 0; r < 16; ++r) a = fmaf(drow[(s << 5) + r], wrow[r], a);
    float dtv = (a > 20.f) ? a : log1pf(__expf(a));
    float du = dtv * xc[s];
    #pragma unroll
    for (int n = 0; n < 8; ++n) {
      float dA = __expf(dtv * Av[n]);
      p[n] *= dA;
      q[n] = fmaf(q[n], dA, du * drow[(s << 5) + 16 + n]);
    }
  }
  size_t ob = (size_t)dir * 1048576 + ((size_t)((b << 8) + ch) << 11) + d;
  #pragma unroll
  for (int n = 0; n < 8; ++n) { P[ob + (n << 8)] = p[n]; Q[ob + (n << 8)] = q[n]; }
}

// ---------------------------------------------------------------------------
// K6: p2a — compose 16 chunks/superchunk. grid 512 = dir x b x n x sup
// ---------------------------------------------------------------------------
__global__ __launch_bounds__(256) void scan_p2a(
    const float* __restrict__ P, const float* __restrict__ Q,
    float* __restrict__ SP, float* __restrict__ SQ)
{
  const int d = threadIdx.x;
  const int bid = blockIdx.x;
  const int dir = bid >> 8, b = (bid >> 7) & 1, n = (bid >> 4) & 7, sup = bid & 15;
  float sp = 1.f, sq = 0.f;
  #pragma unroll 4
  for (int c = 0; c < 16; ++c) {
    int ch = (sup << 4) + c;
    size_t i = (size_t)dir * 1048576 + ((size_t)((b << 8) + ch) << 11) + (n << 8) + d;
    float pp = P[i], qq = Q[i];
    sq = fmaf(pp, sq, qq);
    sp *= pp;
  }
  size_t o2 = ((size_t)((((dir << 1) + b) << 3) + n) << 12) + ((size_t)sup << 8) + d;
  SP[o2] = sp; SQ[o2] = sq;
}

// ---------------------------------------------------------------------------
// K7: p2bc — compose superchunk prefix locally, expand to per-chunk Hs.
// grid 512 = dir x b x n x sup
// ---------------------------------------------------------------------------
__global__ __launch_bounds__(256) void scan_p2bc(
    const float* __restrict__ P, const float* __restrict__ Q,
    const float* __restrict__ SP, const float* __restrict__ SQ,
    float* __restrict__ Hs)
{
  const int d = threadIdx.x;
  const int bid = blockIdx.x;
  const int dir = bid >> 8, b = (bid >> 7) & 1, n = (bid >> 4) & 7, sup = bid & 15;
  size_t sb = ((size_t)((((dir << 1) + b) << 3) + n) << 12) + d;
  float h = 0.f;
  for (int s2 = 0; s2 < sup; ++s2) {
    size_t i = sb + ((size_t)s2 << 8);
    h = fmaf(SP[i], h, SQ[i]);
  }
  #pragma unroll 4
  for (int c = 0; c < 16; ++c) {
    int ch = (sup << 4) + c;
    size_t i = (size_t)dir * 1048576 + ((size_t)((b << 8) + ch) << 11) + (n << 8) + d;
    Hs[i] = h;
    h = fmaf(P[i], h, Q[i]);
  }
}

// ---------------------------------------------------------------------------
// K8: scan phase-3: conv+dt recompute, replay, +x*D, *silu(z), bf16 out.
// grid 1024, 256 threads (d)
// ---------------------------------------------------------------------------
__global__ __launch_bounds__(256) void scan_p3(
    const float* __restrict__ x,
    const float* __restrict__ cw0, const float* __restrict__ cb0,
    const float* __restrict__ cw1, const float* __restrict__ cb1,
    const float* __restrict__ dbl,
    const float* __restrict__ dtw0, const float* __restrict__ dtb0,
    const float* __restrict__ dtw1, const float* __restrict__ dtb1,
    const float* __restrict__ Hs, const float* __restrict__ z,
    const float* __restrict__ Al0, const float* __restrict__ Al1,
    const float* __restrict__ Dp0, const float* __restrict__ Dp1,
    short* __restrict__ yall)
{
  const int d = threadIdx.x;
  const int dir = blockIdx.x >> 9;
  const int b   = (blockIdx.x >> 8) & 1;
  const int ch  = blockIdx.x & 255;
  const int t0  = ch << 4;
  const float* cw   = dir ? cw1 : cw0;
  const float* cb   = dir ? cb1 : cb0;
  const float* dtw  = dir ? dtw1 : dtw0;
  const float* dtb  = dir ? dtb1 : dtb0;
  const float* Alog = dir ? Al1 : Al0;
  const float* Dp   = dir ? Dp1 : Dp0;
  const size_t xb = ((size_t)b) << 12;
  short* y = yall + (size_t)dir * (NTOK * 256);

  float xc[16];
  {
    const float w0 = cw[(d << 2)], w1 = cw[(d << 2) + 1],
                w2 = cw[(d << 2) + 2], w3 = cw[(d << 2) + 3];
    const float bias = cb[d];
    float h0 = 0.f, h1 = 0.f, h2 = 0.f;
    #pragma unroll
    for (int i = 0; i < 3; ++i) {
      int ts = t0 - 3 + i; float v = 0.f;
      if (ts >= 0) { int tn = dir ? 4095 - ts : ts; v = x[(xb + tn) * 256 + d]; }
      h0 = h1; h1 = h2; h2 = v;
    }
    #pragma unroll
    for (int s = 0; s < 16; ++s) {
      int tn = dir ? 4095 - (t0 + s) : (t0 + s);
      float xv = x[(xb + tn) * 256 + d];
      float a = bias + w0 * h0 + w1 * h1 + w2 * h2 + w3 * xv;
      h0 = h1; h1 = h2; h2 = xv;
      xc[s] = a / (1.f + __expf(-a));
    }
  }

  float wrow[16];
  #pragma unroll
  for (int r = 0; r < 16; ++r) wrow[r] = dtw[(d << 4) + r];
  const float bias_dt = dtb[d];
  float Av[8], h[8];
  #pragma unroll
  for (int n = 0; n < 8; ++n) Av[n] = -expf(Alog[(d << 3) + n]);
  size_t hb = (size_t)dir * 1048576 + ((size_t)((b << 8) + ch) << 11) + d;
  #pragma unroll
  for (int n = 0; n < 8; ++n) h[n] = Hs[hb + (n << 8)];
  const float Dv = Dp[d];
  const float* drow = dbl + ((size_t)(dir << 13) + (b << 12) + t0) * 32;  // uniform
  #pragma unroll 4
  for (int s = 0; s < 16; ++s) {
    float a = bias_dt;
    #pragma unroll
    for (int r = 0; r < 16; ++r) a = fmaf(drow[(s << 5) + r], wrow[r], a);
    float dtv = (a > 20.f) ? a : log1pf(__expf(a));
    float du = dtv * xc[s];
    float yv = 0.f;
    #pragma unroll
    for (int n = 0; n < 8; ++n) {
      float dA = __expf(dtv * Av[n]);
      h[n] = fmaf(h[n], dA, du * drow[(s << 5) + 16 + n]);
      yv = fmaf(h[n], drow[(s << 5) + 24 + n], yv);
    }
    yv = fmaf(xc[s], Dv, yv);
    int ts = t0 + s;
    int tn = dir ? (4095 - ts) : ts;
    size_t zi = (xb + tn) * 256 + d;
    float zv = z[zi];
    y[zi] = f2bf(yv * zv / (1.f + __expf(-zv)));
  }
}

// ---------------------------------------------------------------------------
// K9: RMSNorm all 3 heads (mode=blockIdx.y: 0=avg, 1=yf, 2=yb), bf16 in/out
// ---------------------------------------------------------------------------
__global__ __launch_bounds__(256) void rms_all(
    const short* __restrict__ yf, const short* __restrict__ yb,
    const float* __restrict__ w, short* __restrict__ yn)
{
  const int d = threadIdx.x;
  const int mode = blockIdx.y;
  const size_t tok = blockIdx.x;
  size_t i = tok * 256 + d;
  float v;
  if (mode == 0)      v = 0.5f * (bf2f(yf[i]) + bf2f(yb[i]));
  else if (mode == 1) v = bf2f(yf[i]);
  else                v = bf2f(yb[i]);
  float ss = v * v;
  #pragma unroll
  for (int o = 32; o > 0; o >>= 1) ss += __shfl_xor(ss, o, 64);
  __shared__ float red[4];
  if ((d & 63) == 0) red[d >> 6] = ss;
  __syncthreads();
  float tot = red[0] + red[1] + red[2] + red[3];
  float sc = rsqrtf(tot * (1.f / 256.f) + 1e-5f);
  yn[((size_t)mode * 8192 + tok) * 256 + d] = f2bf(v * sc * w[d]);
}

// ---------------------------------------------------------------------------
extern "C" void kernel_launch(void* const* d_in, const int* in_sizes, int n_in,
                              void* d_out, int out_size, void* d_ws, size_t ws_size,
                              hipStream_t stream) {
  const float* in0        = (const float*)d_in[0];
  const float* in1        = (const float*)d_in[1];
  const float* n0w        = (const float*)d_in[2];
  const float* n0b        = (const float*)d_in[3];
  const float* n1w        = (const float*)d_in[4];
  const float* n1b        = (const float*)d_in[5];
  const float* in_proj_w  = (const float*)d_in[6];
  const float* in_projz_w = (const float*)d_in[7];
  const float* conv1d_w   = (const float*)d_in[8];
  const float* conv1d_b   = (const float*)d_in[9];
  const float* conv1db_w  = (const float*)d_in[10];
  const float* conv1db_b  = (const float*)d_in[11];
  const float* xproj_w    = (const float*)d_in[12];
  const float* xprojb_w   = (const float*)d_in[13];
  const float* dtproj_w   = (const float*)d_in[14];
  const float* dtproj_b   = (const float*)d_in[15];
  const float* dtprojb_w  = (const float*)d_in[16];
  const float* dtprojb_b  = (const float*)d_in[17];
  const float* A_log      = (const float*)d_in[18];
  const float* Ab_log     = (const float*)d_in[19];
  const float* D_p        = (const float*)d_in[20];
  const float* D_b        = (const float*)d_in[21];
  const float* rms_w      = (const float*)d_in[22];
  const float* out_proj_w = (const float*)d_in[23];
  const float* conv3d_w   = (const float*)d_in[24];
  const float* conv3d_b   = (const float*)d_in[25];
  (void)in_sizes; (void)n_in; (void)out_size; (void)ws_size;

  float* ws = (float*)d_ws;
  size_t o = 0;
  short* xlnz = (short*)(ws + o); o += 2097152;   // 16384x256 bf16
  float* seqT = ws + o;           o += 2097152;
  float* x    = ws + o;           o += 2097152;   // x then z contiguous
  float* z    = ws + o;           o += 2097152;
  short* xcb  = (short*)(ws + o); o += 2097152;   // 2x8192x256 bf16
  float* dbl  = ws + o;           o += 524288;    // 16384x32 f32
  float* P    = ws + o;           o += 2097152;
  float* Q    = ws + o;           o += 2097152;
  float* Hs   = ws + o;           o += 2097152;
  float* SP   = ws + o;           o += 131072;
  float* SQ   = ws + o;           o += 131072;
  short* yall = (short*)(ws + o); o += 2097152;   // 2x8192x256 bf16
  short* yn   = (short*)(ws + o); o += 3145728;   // 24576x256 bf16
  short* obuf = (short*)(ws + o); o += 3145728;
  short* Wx   = (short*)(ws + o); o += 32768;
  short* Wz   = (short*)(ws + o); o += 32768;
  short* Wo   = (short*)(ws + o); o += 32768;
  short* Wc   = (short*)(ws + o); o += 163840;    // 1280x256 bf16 padded
  short* Wxp  = (short*)(ws + o); o += 8192;      // 2x32x256 bf16
  float* out  = (float*)d_out;

  dim3 blk(256);

  ln_transpose_kernel<<<dim3(256), blk, 0, stream>>>(
      in0, in1, n0w, n0b, n1w, n1b,
      in_proj_w, in_projz_w, out_proj_w, conv3d_w, xproj_w, xprojb_w,
      Wx, Wz, Wo, Wc, Wxp, xlnz, seqT);

  gemm_fast<0><<<dim3(2, 128), blk, 0, stream>>>(xlnz, Wx, Wz, x, nullptr, nullptr, nullptr, 8192);

  conv_silu_b<<<dim3(1024), blk, 0, stream>>>(x, conv1d_w, conv1d_b, conv1db_w, conv1db_b, xcb);

  gemm_n32<<<dim3(256), blk, 0, stream>>>(xcb, Wxp, dbl);

  scan_p1<<<dim3(1024), blk, 0, stream>>>(
      x, conv1d_w, conv1d_b, conv1db_w, conv1db_b, dbl,
      dtproj_w, dtproj_b, dtprojb_w, dtprojb_b, A_log, Ab_log, P, Q);

  scan_p2a<<<dim3(512), blk, 0, stream>>>(P, Q, SP, SQ);
  scan_p2bc<<<dim3(512), blk, 0, stream>>>(P, Q, SP, SQ, Hs);

  scan_p3<<<dim3(1024), blk, 0, stream>>>(
      x, conv1d_w, conv1d_b, conv1db_w, conv1db_b, dbl,
      dtproj_w, dtproj_b, dtprojb_w, dtprojb_b, Hs, z,
      A_log, Ab_log, D_p, D_b, yall);

  rms_all<<<dim3(8192, 3), blk, 0, stream>>>(yall, yall + 2097152, rms_w, yn);
  gemm_fast<1><<<dim3(2, 192), blk, 0, stream>>>(yn, Wo, nullptr, nullptr, obuf, seqT, nullptr, 0);
  gemm_fast<2><<<dim3(10, 192), blk, 0, stream>>>(obuf, Wc, nullptr, out, nullptr, nullptr, conv3d_b, 0);
}